// Round 1
// baseline (1824.064 us; speedup 1.0000x reference)
//
#include <hip/hip_runtime.h>
#include <math.h>

// ---------------------------------------------------------------------------
// Problem constants
//   B=1024, XDIM=62, TWIN=10, INCH=128, MID=256, OUT=512, K=3, K1=10, LIN=512
// ---------------------------------------------------------------------------

__constant__ int cRegIdx[10][9] = {
  {0,1,2,3,4,0,0,0,0},
  {5,6,7,14,15,16,0,0,0},
  {8,9,10,17,18,19,0,0,0},
  {11,12,13,20,21,22,0,0,0},
  {23,24,25,32,33,34,0,0,0},
  {26,27,28,35,36,37,0,0,0},
  {29,30,31,38,39,40,0,0,0},
  {41,42,43,50,51,57,0,0,0},
  {44,45,46,52,53,54,58,59,60},
  {47,48,49,55,56,61,0,0,0}
};
__constant__ int cRegLen[10] = {5,6,6,6,6,6,6,6,9,6};

struct Ptr10 { const float* p[10]; };

__device__ __forceinline__ float gelu_exact(float v){
  return 0.5f * v * (1.0f + erff(v * 0.70710678118654752f));
}

#define MAC16(a4,b4) \
  acc[0][0]=fmaf(a4.x,b4.x,acc[0][0]); acc[0][1]=fmaf(a4.x,b4.y,acc[0][1]); \
  acc[0][2]=fmaf(a4.x,b4.z,acc[0][2]); acc[0][3]=fmaf(a4.x,b4.w,acc[0][3]); \
  acc[1][0]=fmaf(a4.y,b4.x,acc[1][0]); acc[1][1]=fmaf(a4.y,b4.y,acc[1][1]); \
  acc[1][2]=fmaf(a4.y,b4.z,acc[1][2]); acc[1][3]=fmaf(a4.y,b4.w,acc[1][3]); \
  acc[2][0]=fmaf(a4.z,b4.x,acc[2][0]); acc[2][1]=fmaf(a4.z,b4.y,acc[2][1]); \
  acc[2][2]=fmaf(a4.z,b4.z,acc[2][2]); acc[2][3]=fmaf(a4.z,b4.w,acc[2][3]); \
  acc[3][0]=fmaf(a4.w,b4.x,acc[3][0]); acc[3][1]=fmaf(a4.w,b4.y,acc[3][1]); \
  acc[3][2]=fmaf(a4.w,b4.z,acc[3][2]); acc[3][3]=fmaf(a4.w,b4.w,acc[3][3]);

// ---------------------------------------------------------------------------
// 1) g[b,n,c] = (sum_i x[b,n,i,c]*tfe_w[n,i] + tfe_b[n]) * exp(-var_i(x)) (ddof=1)
//    writes g transposed: GT[n][b*128+c]  (62 x 131072)  and Xcat slot 0.
// ---------------------------------------------------------------------------
__global__ __launch_bounds__(128) void k_g(
    const float* __restrict__ x, const float* __restrict__ tw,
    const float* __restrict__ tb, float* __restrict__ gt,
    float* __restrict__ xcat){
  int bid = blockIdx.x;            // b*62 + n
  int b = bid / 62, n = bid - b*62;
  int t = threadIdx.x;             // channel 0..127
  const float* xp = x + (long)bid * 1280 + t;
  float s = 0.f, s2 = 0.f, gv = 0.f;
#pragma unroll
  for (int i = 0; i < 10; i++){
    float v = xp[(long)i*128];
    s += v; s2 = fmaf(v, v, s2);
    gv = fmaf(v, tw[n*10 + i], gv);
  }
  float mean = s * 0.1f;
  float var  = (s2 - 10.f*mean*mean) * (1.f/9.f);   // ddof=1
  float res  = (gv + tb[n]) * expf(-var);
  gt[(long)n*131072 + b*128 + t]   = res;
  xcat[(long)b*23808 + n*384 + t]  = res;           // slot 0
}

// ---------------------------------------------------------------------------
// 2) spread GEMM:  C(62 x 131072) = A62(62x62) @ Gt(62 x 131072)
//    writes Xcat slot `slot`; optionally writes Agt (row-major 62x131072).
// ---------------------------------------------------------------------------
__global__ __launch_bounds__(256) void k_spread_gemm(
    const float* __restrict__ A62, const float* __restrict__ Gt,
    float* __restrict__ Agt, float* __restrict__ xcat, int slot){
  __shared__ float As[16][68];
  __shared__ float Bs[16][68];
  int tid = threadIdx.x;
  int n0 = blockIdx.x * 64;
  int ar = tid >> 2, ac = (tid & 3) << 2;
  int br = tid >> 4, bc = (tid & 15) << 2;
  int tx = tid & 15, ty = tid >> 4;
  float acc[4][4] = {};
  for (int kt = 0; kt < 62; kt += 16){
    float4 av;
    av.x = (ar < 62 && kt+ac+0 < 62) ? A62[ar*62 + kt+ac+0] : 0.f;
    av.y = (ar < 62 && kt+ac+1 < 62) ? A62[ar*62 + kt+ac+1] : 0.f;
    av.z = (ar < 62 && kt+ac+2 < 62) ? A62[ar*62 + kt+ac+2] : 0.f;
    av.w = (ar < 62 && kt+ac+3 < 62) ? A62[ar*62 + kt+ac+3] : 0.f;
    float4 bv = make_float4(0.f,0.f,0.f,0.f);
    int kr = kt + br;
    if (kr < 62) bv = *(const float4*)(Gt + (long)kr*131072 + n0 + bc);
    As[ac+0][ar]=av.x; As[ac+1][ar]=av.y; As[ac+2][ar]=av.z; As[ac+3][ar]=av.w;
    *(float4*)(&Bs[br][bc]) = bv;
    __syncthreads();
#pragma unroll
    for (int k = 0; k < 16; k++){
      float4 a4 = *(const float4*)(&As[k][ty<<2]);
      float4 b4 = *(const float4*)(&Bs[k][tx<<2]);
      MAC16(a4,b4)
    }
    __syncthreads();
  }
  int col = n0 + (tx<<2);
  int b = col >> 7, c = col & 127;
#pragma unroll
  for (int i = 0; i < 4; i++){
    int row = (ty<<2) + i;
    if (row >= 62) continue;
    float4 v = make_float4(acc[i][0], acc[i][1], acc[i][2], acc[i][3]);
    if (Agt) *(float4*)(Agt + (long)row*131072 + col) = v;
    *(float4*)(xcat + (long)b*23808 + row*384 + slot*128 + c) = v;
  }
}

// ---------------------------------------------------------------------------
// 3) region GEMM: g2in[b, z, m] = sum_{l,c} g[b, idx_z[l], c] * rw_z[m,c,l] + regb[z,m]
//    A gathered from GT, B read strided from rw (L2-resident), C strided store.
// ---------------------------------------------------------------------------
__global__ __launch_bounds__(256) void k_gemm_region(
    const float* __restrict__ Gt, Ptr10 rws, const float* __restrict__ regb,
    float* __restrict__ g2in){
  __shared__ float As[16][68];
  __shared__ float Bs[16][68];
  int z = blockIdx.z;
  int L = cRegLen[z];
  int K = L << 7;
  const float* rw = rws.p[z];
  int tid = threadIdx.x;
  int m0 = blockIdx.x * 64;   // batch rows
  int n0 = blockIdx.y * 64;   // output channels
  int ar = tid >> 2, ac = (tid & 3) << 2;
  int nn = tid & 63, kk0 = (tid >> 6) << 2;
  int tx = tid & 15, ty = tid >> 4;
  float acc[4][4] = {};
  for (int kt = 0; kt < K; kt += 16){
    int q = kt + ac;
    int node = cRegIdx[z][q >> 7];
    float4 av = *(const float4*)(Gt + (long)node*131072 + (m0+ar)*128 + (q & 127));
    As[ac+0][ar]=av.x; As[ac+1][ar]=av.y; As[ac+2][ar]=av.z; As[ac+3][ar]=av.w;
#pragma unroll
    for (int u = 0; u < 4; u++){
      int qq = kt + kk0 + u;
      Bs[kk0+u][nn] = rw[(long)(n0+nn)*K + (qq & 127)*L + (qq >> 7)];
    }
    __syncthreads();
#pragma unroll
    for (int k = 0; k < 16; k++){
      float4 a4 = *(const float4*)(&As[k][ty<<2]);
      float4 b4 = *(const float4*)(&Bs[k][tx<<2]);
      MAC16(a4,b4)
    }
    __syncthreads();
  }
  int col = n0 + (tx<<2);
  float4 rb = *(const float4*)(regb + z*256 + col);
#pragma unroll
  for (int i = 0; i < 4; i++){
    int row = m0 + (ty<<2) + i;
    float4 v = make_float4(acc[i][0]+rb.x, acc[i][1]+rb.y, acc[i][2]+rb.z, acc[i][3]+rb.w);
    *(float4*)(g2in + (long)row*2560 + z*256 + col) = v;
  }
}

// ---------------------------------------------------------------------------
// 4) X2cat[b, n, k*256+t] = (A1^k @ g2in[b])[n,t],  k = 0,1,2
// ---------------------------------------------------------------------------
__global__ __launch_bounds__(256) void k_x2cat(
    const float* __restrict__ g2in, const float* __restrict__ A1,
    float* __restrict__ X2){
  __shared__ float sg[2560];
  __shared__ float sA1[100];
  __shared__ float sA2[100];
  int b = blockIdx.x, tid = threadIdx.x;
  for (int i = tid; i < 2560; i += 256) sg[i] = g2in[(long)b*2560 + i];
  if (tid < 100) sA1[tid] = A1[tid];
  __syncthreads();
  if (tid < 100){
    int n = tid/10, m = tid - n*10;
    float a = 0.f;
#pragma unroll
    for (int t = 0; t < 10; t++) a = fmaf(sA1[n*10+t], sA1[t*10+m], a);
    sA2[tid] = a;
  }
  __syncthreads();
  for (int i = tid; i < 2560; i += 256){
    int n = i >> 8, t = i & 255;
    float v1 = 0.f, v2 = 0.f;
#pragma unroll
    for (int m = 0; m < 10; m++){
      float gv = sg[(m<<8) + t];
      v1 = fmaf(sA1[n*10+m], gv, v1);
      v2 = fmaf(sA2[n*10+m], gv, v2);
    }
    long base = (long)b*7680 + n*768;
    X2[base + t]       = sg[i];
    X2[base + 256 + t] = v1;
    X2[base + 512 + t] = v2;
  }
}

// ---------------------------------------------------------------------------
// 5) generic GEMM + ReLU:  C(M x N) = relu(A(M x K) @ Bw(K x N)),
//    M = gridDim.x*64, contiguous layouts. Used for cheby1 and cheby2.
// ---------------------------------------------------------------------------
__global__ __launch_bounds__(256) void k_gemm_relu(
    const float* __restrict__ A, const float* __restrict__ Bw,
    float* __restrict__ C, int K, int N){
  __shared__ float As[16][68];
  __shared__ float Bs[16][68];
  int tid = threadIdx.x;
  int m0 = blockIdx.x * 64, n0 = blockIdx.y * 64;
  int ar = tid >> 2, ac = (tid & 3) << 2;
  int br = tid >> 4, bc = (tid & 15) << 2;
  int tx = tid & 15, ty = tid >> 4;
  float acc[4][4] = {};
  const float* Ap = A + (long)(m0+ar)*K + ac;
  const float* Bp = Bw + (long)br*N + n0 + bc;
  for (int kt = 0; kt < K; kt += 16){
    float4 av = *(const float4*)(Ap + kt);
    float4 bv = *(const float4*)(Bp + (long)kt*N);
    As[ac+0][ar]=av.x; As[ac+1][ar]=av.y; As[ac+2][ar]=av.z; As[ac+3][ar]=av.w;
    *(float4*)(&Bs[br][bc]) = bv;
    __syncthreads();
#pragma unroll
    for (int k = 0; k < 16; k++){
      float4 a4 = *(const float4*)(&As[k][ty<<2]);
      float4 b4 = *(const float4*)(&Bs[k][tx<<2]);
      MAC16(a4,b4)
    }
    __syncthreads();
  }
#pragma unroll
  for (int i = 0; i < 4; i++){
    float4 v = make_float4(fmaxf(acc[i][0],0.f), fmaxf(acc[i][1],0.f),
                           fmaxf(acc[i][2],0.f), fmaxf(acc[i][3],0.f));
    *(float4*)(C + (long)(m0+(ty<<2)+i)*N + n0 + (tx<<2)) = v;
  }
}

// ---------------------------------------------------------------------------
// 6) softmax-gated concat:
//    out[b, j*512+o] = softmax_j(gate_j * cat[b,j,o]) * cat[b,j,o]
//    cat = [g1 (62 rows) ; g2 (10 rows)], gate = b_gate / c_gate.
// ---------------------------------------------------------------------------
__global__ __launch_bounds__(128) void k_softcat(
    const float* __restrict__ g1, const float* __restrict__ g2,
    const float* __restrict__ bg_, const float* __restrict__ cg_,
    float* __restrict__ outb){
  __shared__ float sc[72][128];
  int b = blockIdx.x;
  int oq = blockIdx.y * 128;
  int tid = threadIdx.x;
  int o = oq + tid;
#pragma unroll
  for (int j = 0; j < 62; j++) sc[j][tid] = g1[((long)b*62 + j)*512 + o];
#pragma unroll
  for (int j = 0; j < 10; j++) sc[62+j][tid] = g2[((long)b*10 + j)*512 + o];
  __syncthreads();
  float bg = *bg_, cg = *cg_;
  float mx = -1e30f;
#pragma unroll
  for (int j = 0; j < 72; j++){
    float av = (j < 62 ? bg : cg) * sc[j][tid];
    mx = fmaxf(mx, av);
  }
  float sum = 0.f;
#pragma unroll
  for (int j = 0; j < 72; j++){
    float av = (j < 62 ? bg : cg) * sc[j][tid];
    sum += expf(av - mx);
  }
  float inv = 1.f / sum;
#pragma unroll
  for (int j = 0; j < 72; j++){
    float v = sc[j][tid];
    float av = (j < 62 ? bg : cg) * v;
    outb[(long)b*36864 + j*512 + o] = expf(av - mx) * inv * v;
  }
}

// ---------------------------------------------------------------------------
// 7) split-K GEMM for h1: P[s] = out(1024 x 36864)[:, s-slice] @ hc_w1 slice
// ---------------------------------------------------------------------------
__global__ __launch_bounds__(256) void k_gemm_splitk(
    const float* __restrict__ A, const float* __restrict__ Bw,
    float* __restrict__ P){
  const int K = 36864, N = 512, KS = 4608;
  __shared__ float As[16][68];
  __shared__ float Bs[16][68];
  int tid = threadIdx.x;
  int s = blockIdx.z;
  int kb = s * KS;
  int m0 = blockIdx.x * 64, n0 = blockIdx.y * 64;
  int ar = tid >> 2, ac = (tid & 3) << 2;
  int br = tid >> 4, bc = (tid & 15) << 2;
  int tx = tid & 15, ty = tid >> 4;
  float acc[4][4] = {};
  const float* Ap = A + (long)(m0+ar)*K + kb + ac;
  const float* Bp = Bw + (long)(kb+br)*N + n0 + bc;
  for (int kt = 0; kt < KS; kt += 16){
    float4 av = *(const float4*)(Ap + kt);
    float4 bv = *(const float4*)(Bp + (long)kt*N);
    As[ac+0][ar]=av.x; As[ac+1][ar]=av.y; As[ac+2][ar]=av.z; As[ac+3][ar]=av.w;
    *(float4*)(&Bs[br][bc]) = bv;
    __syncthreads();
#pragma unroll
    for (int k = 0; k < 16; k++){
      float4 a4 = *(const float4*)(&As[k][ty<<2]);
      float4 b4 = *(const float4*)(&Bs[k][tx<<2]);
      MAC16(a4,b4)
    }
    __syncthreads();
  }
  float* Cp = P + (long)s*524288;
#pragma unroll
  for (int i = 0; i < 4; i++){
    float4 v = make_float4(acc[i][0], acc[i][1], acc[i][2], acc[i][3]);
    *(float4*)(Cp + (long)(m0+(ty<<2)+i)*512 + n0 + (tx<<2)) = v;
  }
}

// 8) reduce split-K partials + bias -> h1 (1024 x 512)
__global__ __launch_bounds__(256) void k_reduce(
    const float* __restrict__ P, const float* __restrict__ bias,
    float* __restrict__ h1){
  int idx = blockIdx.x*256 + threadIdx.x;   // 0 .. 524287
  float v = bias[idx & 511];
#pragma unroll
  for (int s = 0; s < 8; s++) v += P[(long)s*524288 + idx];
  h1[idx] = v;
}

// 9) batch-norm stats over batch dim (ddof=0): mu[j], rsig[j]=rsqrt(var+1e-5)
__global__ __launch_bounds__(256) void k_stats(
    const float* __restrict__ h, int N, float* __restrict__ mu,
    float* __restrict__ rs){
  int j = blockIdx.x;
  int tid = threadIdx.x;
  float s = 0.f, s2 = 0.f;
  for (int b = tid; b < 1024; b += 256){
    float v = h[(long)b*N + j];
    s += v; s2 = fmaf(v, v, s2);
  }
#pragma unroll
  for (int o = 32; o > 0; o >>= 1){
    s  += __shfl_down(s, o);
    s2 += __shfl_down(s2, o);
  }
  __shared__ float aa[4], bb[4];
  int w = tid >> 6;
  if ((tid & 63) == 0){ aa[w] = s; bb[w] = s2; }
  __syncthreads();
  if (tid == 0){
    s  = aa[0]+aa[1]+aa[2]+aa[3];
    s2 = bb[0]+bb[1]+bb[2]+bb[3];
    float m = s * (1.f/1024.f);
    float var = s2 * (1.f/1024.f) - m*m;
    mu[j] = m;
    rs[j] = rsqrtf(var + 1e-5f);
  }
}

// 10) h2 = gelu(bn1(h1)) @ hc_w2 + hc_b2   (BN+GELU applied on A-load)
__global__ __launch_bounds__(256) void k_gemm_h2(
    const float* __restrict__ A, const float* __restrict__ Bw,
    const float* __restrict__ mu, const float* __restrict__ rs,
    const float* __restrict__ gam, const float* __restrict__ bet,
    const float* __restrict__ bias, float* __restrict__ C){
  const int K = 512, N = 256;
  __shared__ float As[16][68];
  __shared__ float Bs[16][68];
  int tid = threadIdx.x;
  int m0 = blockIdx.x * 64, n0 = blockIdx.y * 64;
  int ar = tid >> 2, ac = (tid & 3) << 2;
  int br = tid >> 4, bc = (tid & 15) << 2;
  int tx = tid & 15, ty = tid >> 4;
  float acc[4][4] = {};
  const float* Ap = A + (long)(m0+ar)*K + ac;
  const float* Bp = Bw + (long)br*N + n0 + bc;
  for (int kt = 0; kt < K; kt += 16){
    float4 av = *(const float4*)(Ap + kt);
    int kc = kt + ac;
    av.x = gelu_exact((av.x - mu[kc+0])*rs[kc+0]*gam[kc+0] + bet[kc+0]);
    av.y = gelu_exact((av.y - mu[kc+1])*rs[kc+1]*gam[kc+1] + bet[kc+1]);
    av.z = gelu_exact((av.z - mu[kc+2])*rs[kc+2]*gam[kc+2] + bet[kc+2]);
    av.w = gelu_exact((av.w - mu[kc+3])*rs[kc+3]*gam[kc+3] + bet[kc+3]);
    float4 bv = *(const float4*)(Bp + (long)kt*N);
    As[ac+0][ar]=av.x; As[ac+1][ar]=av.y; As[ac+2][ar]=av.z; As[ac+3][ar]=av.w;
    *(float4*)(&Bs[br][bc]) = bv;
    __syncthreads();
#pragma unroll
    for (int k = 0; k < 16; k++){
      float4 a4 = *(const float4*)(&As[k][ty<<2]);
      float4 b4 = *(const float4*)(&Bs[k][tx<<2]);
      MAC16(a4,b4)
    }
    __syncthreads();
  }
  int col = n0 + (tx<<2);
  float4 bb = *(const float4*)(bias + col);
#pragma unroll
  for (int i = 0; i < 4; i++){
    float4 v = make_float4(acc[i][0]+bb.x, acc[i][1]+bb.y, acc[i][2]+bb.z, acc[i][3]+bb.w);
    *(float4*)(C + (long)(m0+(ty<<2)+i)*N + col) = v;
  }
}

// 11) final: bn2+gelu, @ hc_w3 + hc_b3, softmax over 4 -> d_out
__global__ __launch_bounds__(256) void k_final(
    const float* __restrict__ h2, const float* __restrict__ mu,
    const float* __restrict__ rs, const float* __restrict__ gam,
    const float* __restrict__ bet, const float* __restrict__ w3,
    const float* __restrict__ b3, float* __restrict__ outp){
  int b = blockIdx.x, tid = threadIdx.x;
  float v = h2[(long)b*256 + tid];
  v = (v - mu[tid]) * rs[tid] * gam[tid] + bet[tid];
  v = gelu_exact(v);
  float4 w = ((const float4*)w3)[tid];
  float p0 = v*w.x, p1 = v*w.y, p2 = v*w.z, p3 = v*w.w;
#pragma unroll
  for (int o = 32; o > 0; o >>= 1){
    p0 += __shfl_down(p0, o);
    p1 += __shfl_down(p1, o);
    p2 += __shfl_down(p2, o);
    p3 += __shfl_down(p3, o);
  }
  __shared__ float red[4][4];
  int wv = tid >> 6;
  if ((tid & 63) == 0){ red[wv][0]=p0; red[wv][1]=p1; red[wv][2]=p2; red[wv][3]=p3; }
  __syncthreads();
  if (tid == 0){
    float l[4];
#pragma unroll
    for (int c = 0; c < 4; c++)
      l[c] = red[0][c]+red[1][c]+red[2][c]+red[3][c] + b3[c];
    float m = fmaxf(fmaxf(l[0], l[1]), fmaxf(l[2], l[3]));
    float e[4]; float sum = 0.f;
#pragma unroll
    for (int c = 0; c < 4; c++){ e[c] = expf(l[c]-m); sum += e[c]; }
    float inv = 1.f / sum;
#pragma unroll
    for (int c = 0; c < 4; c++) outp[(long)b*4 + c] = e[c]*inv;
  }
}

// ---------------------------------------------------------------------------
// Workspace layout (float offsets). Peak ~309 MB with aliasing:
//   GT 0(8.1M) | XCAT 8.1M(24.4M) | G2IN 32.5M(2.6M) | AGT/X2CAT 35.1M(8.1M)
//   OUT aliases [0..37.7M) after all of the above are dead.
//   G1 43.25M(32.5M) | G2 75.76M(5.2M) | P/H1/H2/stats alias G1 after softcat.
// ---------------------------------------------------------------------------
extern "C" void kernel_launch(void* const* d_in, const int* in_sizes, int n_in,
                              void* d_out, int out_size, void* d_ws, size_t ws_size,
                              hipStream_t stream){
  (void)n_in; (void)out_size; (void)ws_size;
  bool dictOrder = (in_sizes[9] == 2560);   // region_b at 9 (dict) vs rw1 (arg order)
  const float* x     = (const float*)d_in[0];
  const float* tfe_w = (const float*)d_in[1];
  const float* tfe_b = (const float*)d_in[2];
  const float* ch1w  = (const float*)d_in[3];
  const float* Amat  = (const float*)d_in[4];
  const float* ch2w  = (const float*)d_in[5];
  const float* A1mat = (const float*)d_in[6];
  const float* bgate = (const float*)d_in[7];
  const float* cgate = (const float*)d_in[8];
  const float* regb  = (const float*)d_in[dictOrder ? 9 : 19];
  int o = dictOrder ? 0 : 10;
  const float* hc_w1 = (const float*)d_in[10+o];
  const float* hc_b1 = (const float*)d_in[11+o];
  const float* bn1g  = (const float*)d_in[12+o];
  const float* bn1b  = (const float*)d_in[13+o];
  const float* hc_w2 = (const float*)d_in[14+o];
  const float* hc_b2 = (const float*)d_in[15+o];
  const float* bn2g  = (const float*)d_in[16+o];
  const float* bn2b  = (const float*)d_in[17+o];
  const float* hc_w3 = (const float*)d_in[18+o];
  const float* hc_b3 = (const float*)d_in[19+o];
  Ptr10 rws;
  for (int i = 0; i < 10; i++) rws.p[i] = (const float*)d_in[(dictOrder ? 20 : 9) + i];

  float* W     = (float*)d_ws;
  float* GT    = W + 0;
  float* XCAT  = W + 8126464;
  float* G2IN  = W + 32505856;
  float* AGT   = W + 35127296;
  float* X2CAT = W + 35127296;   // aliases AGT (dead by then)
  float* OUTB  = W + 0;          // aliases GT/XCAT/G2IN/X2CAT (all dead by then)
  float* G1    = W + 43253760;
  float* G2    = W + 75759616;
  float* P     = W + 43253760;   // aliases G1 (dead after softcat)
  float* H1    = W + 47448064;
  float* H2    = W + 47972352;
  float* MU1   = W + 48234496;
  float* RS1   = MU1 + 512;
  float* MU2   = MU1 + 1024;
  float* RS2   = MU1 + 1280;

  k_g<<<1024*62, 128, 0, stream>>>(x, tfe_w, tfe_b, GT, XCAT);
  k_spread_gemm<<<2048, 256, 0, stream>>>(Amat, GT, AGT, XCAT, 1);
  k_spread_gemm<<<2048, 256, 0, stream>>>(Amat, AGT, nullptr, XCAT, 2);
  k_gemm_region<<<dim3(16,4,10), 256, 0, stream>>>(GT, rws, regb, G2IN);
  k_x2cat<<<1024, 256, 0, stream>>>(G2IN, A1mat, X2CAT);
  k_gemm_relu<<<dim3(160,8), 256, 0, stream>>>(X2CAT, ch2w, G2, 768, 512);
  k_gemm_relu<<<dim3(992,8), 256, 0, stream>>>(XCAT, ch1w, G1, 384, 512);
  k_softcat<<<dim3(1024,4), 128, 0, stream>>>(G1, G2, bgate, cgate, OUTB);
  k_gemm_splitk<<<dim3(16,8,8), 256, 0, stream>>>(OUTB, hc_w1, P);
  k_reduce<<<2048, 256, 0, stream>>>(P, hc_b1, H1);
  k_stats<<<512, 256, 0, stream>>>(H1, 512, MU1, RS1);
  k_gemm_h2<<<dim3(16,4), 256, 0, stream>>>(H1, hc_w2, MU1, RS1, bn1g, bn1b, hc_b2, H2);
  k_stats<<<256, 256, 0, stream>>>(H2, 256, MU2, RS2);
  k_final<<<1024, 256, 0, stream>>>(H2, MU2, RS2, bn2g, bn2b, hc_w3, hc_b3, (float*)d_out);
}

// Round 2
// 1012.028 us; speedup vs baseline: 1.8024x; 1.8024x over previous
//
#include <hip/hip_runtime.h>
#include <math.h>

// ---------------------------------------------------------------------------
// Problem constants: B=1024, XDIM=62, TWIN=10, INCH=128, MID=256, OUT=512,
// K=3, K1=10, LIN=512
// ---------------------------------------------------------------------------

__constant__ int cRegIdx[10][9] = {
  {0,1,2,3,4,0,0,0,0},
  {5,6,7,14,15,16,0,0,0},
  {8,9,10,17,18,19,0,0,0},
  {11,12,13,20,21,22,0,0,0},
  {23,24,25,32,33,34,0,0,0},
  {26,27,28,35,36,37,0,0,0},
  {29,30,31,38,39,40,0,0,0},
  {41,42,43,50,51,57,0,0,0},
  {44,45,46,52,53,54,58,59,60},
  {47,48,49,55,56,61,0,0,0}
};
__constant__ int cRegLen[10] = {5,6,6,6,6,6,6,6,9,6};

struct Ptr10 { const float* p[10]; };

typedef __attribute__((ext_vector_type(8))) short bf16x8;
typedef __attribute__((ext_vector_type(4))) float f32x4;

__device__ __forceinline__ float gelu_exact(float v){
  return 0.5f * v * (1.0f + erff(v * 0.70710678118654752f));
}
__device__ __forceinline__ unsigned short f2bf(float f){
  unsigned u = __float_as_uint(f);
  unsigned r = (u + 0x7fffu + ((u >> 16) & 1u)) >> 16;
  return (unsigned short)r;
}
__device__ __forceinline__ float bf2f(unsigned short u){
  return __uint_as_float(((unsigned)u) << 16);
}
__device__ __forceinline__ void load_lds16(const unsigned short* g, unsigned short* l){
  __builtin_amdgcn_global_load_lds(
      (const __attribute__((address_space(1))) void*)g,
      (__attribute__((address_space(3))) void*)l, 16, 0, 0);
}

#define MAC16(a4,b4) \
  acc[0][0]=fmaf(a4.x,b4.x,acc[0][0]); acc[0][1]=fmaf(a4.x,b4.y,acc[0][1]); \
  acc[0][2]=fmaf(a4.x,b4.z,acc[0][2]); acc[0][3]=fmaf(a4.x,b4.w,acc[0][3]); \
  acc[1][0]=fmaf(a4.y,b4.x,acc[1][0]); acc[1][1]=fmaf(a4.y,b4.y,acc[1][1]); \
  acc[1][2]=fmaf(a4.y,b4.z,acc[1][2]); acc[1][3]=fmaf(a4.y,b4.w,acc[1][3]); \
  acc[2][0]=fmaf(a4.z,b4.x,acc[2][0]); acc[2][1]=fmaf(a4.z,b4.y,acc[2][1]); \
  acc[2][2]=fmaf(a4.z,b4.z,acc[2][2]); acc[2][3]=fmaf(a4.z,b4.w,acc[2][3]); \
  acc[3][0]=fmaf(a4.w,b4.x,acc[3][0]); acc[3][1]=fmaf(a4.w,b4.y,acc[3][1]); \
  acc[3][2]=fmaf(a4.w,b4.z,acc[3][2]); acc[3][3]=fmaf(a4.w,b4.w,acc[3][3]);

// ---------------------------------------------------------------------------
// MFMA GEMM: C(MxN) = A(MxK) @ BT(NxK)^T, bf16 inputs, fp32 accumulate.
// 128x128 tile per block (256 thr = 4 waves, each wave 64x64 = 4x4 MFMA 16x16x32).
// LDS: A-tile [128][32] bf16 + B^T-tile [128][32] bf16, XOR-swizzled 16B chunks
// (chunk' = chunk ^ (row&3)) -> 2-way bank aliasing (free). Staged with
// global_load_lds width=16. Single-buffered m97 structure.
// RELU=true  -> store bf16 with relu (cheby outputs)
// RELU=false -> store fp32 partials at Cv + z*cStrideZ (split-K for h1)
// ---------------------------------------------------------------------------
template<bool RELU>
__global__ __launch_bounds__(256) void k_mfma(
    const unsigned short* __restrict__ A, long lda,
    const unsigned short* __restrict__ BT, long ldb,
    void* __restrict__ Cv, int ldc, int kPerZ, long cStrideZ){
  __shared__ unsigned short As[128*32];
  __shared__ unsigned short Bs[128*32];
  int tid = threadIdx.x;
  int wave = tid >> 6, lane = tid & 63;
  int m0 = blockIdx.x * 128, n0 = blockIdx.y * 128;
  int kStart = blockIdx.z * kPerZ;
  int waveM = wave >> 1, waveN = wave & 1;
  int lr = lane >> 2, ch = lane & 3;       // staging: local row, chunk pos
  int quad = lane >> 4, mrow = lane & 15;  // fragment indices
  int swe = ((quad ^ (mrow & 3)) << 3);    // frag read swizzle, elements

  int rA0 = wave*32 + lr;                  // staging rows (tile-local)
  int rA1 = rA0 + 16;
  int ce  = ((ch ^ (rA0 & 3)) << 3);       // staged chunk, elements (rA1&3==rA0&3)
  const unsigned short* gA0 = A  + (long)(m0 + rA0)*lda + kStart + ce;
  const unsigned short* gA1 = A  + (long)(m0 + rA1)*lda + kStart + ce;
  const unsigned short* gB0 = BT + (long)(n0 + rA0)*ldb + kStart + ce;
  const unsigned short* gB1 = BT + (long)(n0 + rA1)*ldb + kStart + ce;
  unsigned short* lA0 = &As[(wave*32)*32];
  unsigned short* lA1 = &As[(wave*32+16)*32];
  unsigned short* lB0 = &Bs[(wave*32)*32];
  unsigned short* lB1 = &Bs[(wave*32+16)*32];

  f32x4 acc[4][4] = {};
  int nIter = kPerZ >> 5;
  for (int it = 0; it < nIter; ++it){
    long ko = (long)it << 5;
    load_lds16(gA0 + ko, lA0);
    load_lds16(gA1 + ko, lA1);
    load_lds16(gB0 + ko, lB0);
    load_lds16(gB1 + ko, lB1);
    __syncthreads();
    bf16x8 af[4], bfr[4];
#pragma unroll
    for (int mi = 0; mi < 4; mi++)
      af[mi] = *(const bf16x8*)&As[(waveM*64 + mi*16 + mrow)*32 + swe];
#pragma unroll
    for (int ni = 0; ni < 4; ni++)
      bfr[ni] = *(const bf16x8*)&Bs[(waveN*64 + ni*16 + mrow)*32 + swe];
#pragma unroll
    for (int mi = 0; mi < 4; mi++)
#pragma unroll
      for (int ni = 0; ni < 4; ni++)
        acc[mi][ni] = __builtin_amdgcn_mfma_f32_16x16x32_bf16(
            af[mi], bfr[ni], acc[mi][ni], 0, 0, 0);
    __syncthreads();
  }
  // epilogue: C/D layout col=lane&15, row=quad*4+r
  if (RELU){
    unsigned short* C = (unsigned short*)Cv;
#pragma unroll
    for (int mi = 0; mi < 4; mi++)
#pragma unroll
      for (int ni = 0; ni < 4; ni++){
        int col = n0 + waveN*64 + ni*16 + mrow;
#pragma unroll
        for (int r = 0; r < 4; r++){
          int row = m0 + waveM*64 + mi*16 + quad*4 + r;
          C[(long)row*ldc + col] = f2bf(fmaxf(acc[mi][ni][r], 0.f));
        }
      }
  } else {
    float* C = (float*)Cv + (long)blockIdx.z * cStrideZ;
#pragma unroll
    for (int mi = 0; mi < 4; mi++)
#pragma unroll
      for (int ni = 0; ni < 4; ni++){
        int col = n0 + waveN*64 + ni*16 + mrow;
#pragma unroll
        for (int r = 0; r < 4; r++){
          int row = m0 + waveM*64 + mi*16 + quad*4 + r;
          C[(long)row*ldc + col] = acc[mi][ni][r];
        }
      }
  }
}
template __global__ void k_mfma<true>(const unsigned short*, long, const unsigned short*, long, void*, int, int, long);
template __global__ void k_mfma<false>(const unsigned short*, long, const unsigned short*, long, void*, int, int, long);

// ---------------------------------------------------------------------------
// Transpose fp32 (R x C) -> bf16 (C x R)
// ---------------------------------------------------------------------------
__global__ __launch_bounds__(256) void k_transpose_bf16(
    const float* __restrict__ src, unsigned short* __restrict__ dst, int R, int C){
  __shared__ float t[32][33];
  int c0 = blockIdx.x * 32, r0 = blockIdx.y * 32;
  int tx = threadIdx.x & 31, ty = threadIdx.x >> 5;
#pragma unroll
  for (int i = 0; i < 4; i++){
    int r = ty + i*8;
    t[r][tx] = src[(long)(r0+r)*C + c0 + tx];
  }
  __syncthreads();
#pragma unroll
  for (int i = 0; i < 4; i++){
    int cc = ty + i*8;
    dst[(long)(c0+cc)*R + r0 + tx] = f2bf(t[tx][cc]);
  }
}

// ---------------------------------------------------------------------------
// 1) g[b,n,c] = (sum_i x[b,n,i,c]*tfe_w[n,i] + tfe_b[n]) * exp(-var_i(x)) (ddof=1)
//    GT fp32 [n][b*128+c] (for region gemm); XCAT slot0 bf16 (cheby1 A)
// ---------------------------------------------------------------------------
__global__ __launch_bounds__(128) void k_g(
    const float* __restrict__ x, const float* __restrict__ tw,
    const float* __restrict__ tb, float* __restrict__ gt,
    unsigned short* __restrict__ xcat){
  int bid = blockIdx.x;            // b*62 + n
  int b = bid / 62, n = bid - b*62;
  int t = threadIdx.x;             // channel 0..127
  const float* xp = x + (long)bid * 1280 + t;
  float s = 0.f, s2 = 0.f, gv = 0.f;
#pragma unroll
  for (int i = 0; i < 10; i++){
    float v = xp[(long)i*128];
    s += v; s2 = fmaf(v, v, s2);
    gv = fmaf(v, tw[n*10 + i], gv);
  }
  float mean = s * 0.1f;
  float var  = (s2 - 10.f*mean*mean) * (1.f/9.f);   // ddof=1
  float res  = (gv + tb[n]) * expf(-var);
  gt[(long)n*131072 + b*128 + t]  = res;
  xcat[(long)b*23808 + n*384 + t] = f2bf(res);
}

// ---------------------------------------------------------------------------
// 2) spread GEMM: C(62 x 131072) = A62(62x62) @ Gt(62 x 131072); fp32.
//    bf16 into XCAT slot; optional fp32 Agt for the second hop.
// ---------------------------------------------------------------------------
__global__ __launch_bounds__(256) void k_spread_gemm(
    const float* __restrict__ A62, const float* __restrict__ Gt,
    float* __restrict__ Agt, unsigned short* __restrict__ xcat, int slot){
  __shared__ float As[16][68];
  __shared__ float Bs[16][68];
  int tid = threadIdx.x;
  int n0 = blockIdx.x * 64;
  int ar = tid >> 2, ac = (tid & 3) << 2;
  int br = tid >> 4, bc = (tid & 15) << 2;
  int tx = tid & 15, ty = tid >> 4;
  float acc[4][4] = {};
  for (int kt = 0; kt < 62; kt += 16){
    float4 av;
    av.x = (ar < 62 && kt+ac+0 < 62) ? A62[ar*62 + kt+ac+0] : 0.f;
    av.y = (ar < 62 && kt+ac+1 < 62) ? A62[ar*62 + kt+ac+1] : 0.f;
    av.z = (ar < 62 && kt+ac+2 < 62) ? A62[ar*62 + kt+ac+2] : 0.f;
    av.w = (ar < 62 && kt+ac+3 < 62) ? A62[ar*62 + kt+ac+3] : 0.f;
    float4 bv = make_float4(0.f,0.f,0.f,0.f);
    int kr = kt + br;
    if (kr < 62) bv = *(const float4*)(Gt + (long)kr*131072 + n0 + bc);
    As[ac+0][ar]=av.x; As[ac+1][ar]=av.y; As[ac+2][ar]=av.z; As[ac+3][ar]=av.w;
    *(float4*)(&Bs[br][bc]) = bv;
    __syncthreads();
#pragma unroll
    for (int k = 0; k < 16; k++){
      float4 a4 = *(const float4*)(&As[k][ty<<2]);
      float4 b4 = *(const float4*)(&Bs[k][tx<<2]);
      MAC16(a4,b4)
    }
    __syncthreads();
  }
  int col = n0 + (tx<<2);
  int b = col >> 7, c = col & 127;
#pragma unroll
  for (int i = 0; i < 4; i++){
    int row = (ty<<2) + i;
    if (row >= 62) continue;
    if (Agt) *(float4*)(Agt + (long)row*131072 + col) =
        make_float4(acc[i][0], acc[i][1], acc[i][2], acc[i][3]);
    ushort4 u = make_ushort4(f2bf(acc[i][0]), f2bf(acc[i][1]),
                             f2bf(acc[i][2]), f2bf(acc[i][3]));
    *(ushort4*)(xcat + (long)b*23808 + row*384 + slot*128 + c) = u;
  }
}

// ---------------------------------------------------------------------------
// 3) region GEMM (fp32): g2in[b,z,m] = sum_{l,c} g[b,idx_z[l],c]*rw_z[m,c,l] + regb
// ---------------------------------------------------------------------------
__global__ __launch_bounds__(256) void k_gemm_region(
    const float* __restrict__ Gt, Ptr10 rws, const float* __restrict__ regb,
    float* __restrict__ g2in){
  __shared__ float As[16][68];
  __shared__ float Bs[16][68];
  int z = blockIdx.z;
  int L = cRegLen[z];
  int K = L << 7;
  const float* rw = rws.p[z];
  int tid = threadIdx.x;
  int m0 = blockIdx.x * 64;   // batch rows
  int n0 = blockIdx.y * 64;   // output channels
  int ar = tid >> 2, ac = (tid & 3) << 2;
  int nn = tid & 63, kk0 = (tid >> 6) << 2;
  int tx = tid & 15, ty = tid >> 4;
  float acc[4][4] = {};
  for (int kt = 0; kt < K; kt += 16){
    int q = kt + ac;
    int node = cRegIdx[z][q >> 7];
    float4 av = *(const float4*)(Gt + (long)node*131072 + (m0+ar)*128 + (q & 127));
    As[ac+0][ar]=av.x; As[ac+1][ar]=av.y; As[ac+2][ar]=av.z; As[ac+3][ar]=av.w;
#pragma unroll
    for (int u = 0; u < 4; u++){
      int qq = kt + kk0 + u;
      Bs[kk0+u][nn] = rw[(long)(n0+nn)*K + (qq & 127)*L + (qq >> 7)];
    }
    __syncthreads();
#pragma unroll
    for (int k = 0; k < 16; k++){
      float4 a4 = *(const float4*)(&As[k][ty<<2]);
      float4 b4 = *(const float4*)(&Bs[k][tx<<2]);
      MAC16(a4,b4)
    }
    __syncthreads();
  }
  int col = n0 + (tx<<2);
  float4 rb = *(const float4*)(regb + z*256 + col);
#pragma unroll
  for (int i = 0; i < 4; i++){
    int row = m0 + (ty<<2) + i;
    float4 v = make_float4(acc[i][0]+rb.x, acc[i][1]+rb.y, acc[i][2]+rb.z, acc[i][3]+rb.w);
    *(float4*)(g2in + (long)row*2560 + z*256 + col) = v;
  }
}

// ---------------------------------------------------------------------------
// 4) X2cat[b, n, k*256+t] = (A1^k @ g2in[b])[n,t], k=0..2  (bf16 out)
// ---------------------------------------------------------------------------
__global__ __launch_bounds__(256) void k_x2cat(
    const float* __restrict__ g2in, const float* __restrict__ A1,
    unsigned short* __restrict__ X2){
  __shared__ float sg[2560];
  __shared__ float sA1[100];
  __shared__ float sA2[100];
  int b = blockIdx.x, tid = threadIdx.x;
  for (int i = tid; i < 2560; i += 256) sg[i] = g2in[(long)b*2560 + i];
  if (tid < 100) sA1[tid] = A1[tid];
  __syncthreads();
  if (tid < 100){
    int n = tid/10, m = tid - n*10;
    float a = 0.f;
#pragma unroll
    for (int t = 0; t < 10; t++) a = fmaf(sA1[n*10+t], sA1[t*10+m], a);
    sA2[tid] = a;
  }
  __syncthreads();
  for (int i = tid; i < 2560; i += 256){
    int n = i >> 8, t = i & 255;
    float v1 = 0.f, v2 = 0.f;
#pragma unroll
    for (int m = 0; m < 10; m++){
      float gv = sg[(m<<8) + t];
      v1 = fmaf(sA1[n*10+m], gv, v1);
      v2 = fmaf(sA2[n*10+m], gv, v2);
    }
    long base = (long)b*7680 + n*768;
    X2[base + t]       = f2bf(sg[i]);
    X2[base + 256 + t] = f2bf(v1);
    X2[base + 512 + t] = f2bf(v2);
  }
}

// ---------------------------------------------------------------------------
// 6) softmax-gated concat (bf16 in, bf16 out for the h1 MFMA A operand)
// ---------------------------------------------------------------------------
__global__ __launch_bounds__(128) void k_softcat(
    const unsigned short* __restrict__ g1, const unsigned short* __restrict__ g2,
    const float* __restrict__ bg_, const float* __restrict__ cg_,
    unsigned short* __restrict__ outb){
  __shared__ float sc[72][128];
  int b = blockIdx.x;
  int oq = blockIdx.y * 128;
  int tid = threadIdx.x;
  int o = oq + tid;
#pragma unroll
  for (int j = 0; j < 62; j++) sc[j][tid] = bf2f(g1[((long)b*62 + j)*512 + o]);
#pragma unroll
  for (int j = 0; j < 10; j++) sc[62+j][tid] = bf2f(g2[((long)b*10 + j)*512 + o]);
  __syncthreads();
  float bg = *bg_, cg = *cg_;
  float mx = -1e30f;
#pragma unroll
  for (int j = 0; j < 72; j++){
    float av = (j < 62 ? bg : cg) * sc[j][tid];
    mx = fmaxf(mx, av);
  }
  float sum = 0.f;
#pragma unroll
  for (int j = 0; j < 72; j++){
    float av = (j < 62 ? bg : cg) * sc[j][tid];
    sum += expf(av - mx);
  }
  float inv = 1.f / sum;
#pragma unroll
  for (int j = 0; j < 72; j++){
    float v = sc[j][tid];
    float av = (j < 62 ? bg : cg) * v;
    outb[(long)b*36864 + j*512 + o] = f2bf(expf(av - mx) * inv * v);
  }
}

// 8) reduce 16 split-K partials + bias -> h1 (1024 x 512) fp32
__global__ __launch_bounds__(256) void k_reduce(
    const float* __restrict__ P, const float* __restrict__ bias,
    float* __restrict__ h1){
  int idx = blockIdx.x*256 + threadIdx.x;   // 0 .. 524287
  float v = bias[idx & 511];
#pragma unroll
  for (int s = 0; s < 16; s++) v += P[(long)s*524288 + idx];
  h1[idx] = v;
}

// 9) batch-norm stats over batch dim (ddof=0)
__global__ __launch_bounds__(256) void k_stats(
    const float* __restrict__ h, int N, float* __restrict__ mu,
    float* __restrict__ rs){
  int j = blockIdx.x;
  int tid = threadIdx.x;
  float s = 0.f, s2 = 0.f;
  for (int b = tid; b < 1024; b += 256){
    float v = h[(long)b*N + j];
    s += v; s2 = fmaf(v, v, s2);
  }
#pragma unroll
  for (int o = 32; o > 0; o >>= 1){
    s  += __shfl_down(s, o);
    s2 += __shfl_down(s2, o);
  }
  __shared__ float aa[4], bb[4];
  int w = tid >> 6;
  if ((tid & 63) == 0){ aa[w] = s; bb[w] = s2; }
  __syncthreads();
  if (tid == 0){
    s  = aa[0]+aa[1]+aa[2]+aa[3];
    s2 = bb[0]+bb[1]+bb[2]+bb[3];
    float m = s * (1.f/1024.f);
    float var = s2 * (1.f/1024.f) - m*m;
    mu[j] = m;
    rs[j] = rsqrtf(var + 1e-5f);
  }
}

// 10) h2 = gelu(bn1(h1)) @ hc_w2 + hc_b2 (fp32, BN+GELU fused on A-load)
__global__ __launch_bounds__(256) void k_gemm_h2(
    const float* __restrict__ A, const float* __restrict__ Bw,
    const float* __restrict__ mu, const float* __restrict__ rs,
    const float* __restrict__ gam, const float* __restrict__ bet,
    const float* __restrict__ bias, float* __restrict__ C){
  const int K = 512, N = 256;
  __shared__ float As[16][68];
  __shared__ float Bs[16][68];
  int tid = threadIdx.x;
  int m0 = blockIdx.x * 64, n0 = blockIdx.y * 64;
  int ar = tid >> 2, ac = (tid & 3) << 2;
  int br = tid >> 4, bc = (tid & 15) << 2;
  int tx = tid & 15, ty = tid >> 4;
  float acc[4][4] = {};
  const float* Ap = A + (long)(m0+ar)*K + ac;
  const float* Bp = Bw + (long)br*N + n0 + bc;
  for (int kt = 0; kt < K; kt += 16){
    float4 av = *(const float4*)(Ap + kt);
    int kc = kt + ac;
    av.x = gelu_exact((av.x - mu[kc+0])*rs[kc+0]*gam[kc+0] + bet[kc+0]);
    av.y = gelu_exact((av.y - mu[kc+1])*rs[kc+1]*gam[kc+1] + bet[kc+1]);
    av.z = gelu_exact((av.z - mu[kc+2])*rs[kc+2]*gam[kc+2] + bet[kc+2]);
    av.w = gelu_exact((av.w - mu[kc+3])*rs[kc+3]*gam[kc+3] + bet[kc+3]);
    float4 bv = *(const float4*)(Bp + (long)kt*N);
    As[ac+0][ar]=av.x; As[ac+1][ar]=av.y; As[ac+2][ar]=av.z; As[ac+3][ar]=av.w;
    *(float4*)(&Bs[br][bc]) = bv;
    __syncthreads();
#pragma unroll
    for (int k = 0; k < 16; k++){
      float4 a4 = *(const float4*)(&As[k][ty<<2]);
      float4 b4 = *(const float4*)(&Bs[k][tx<<2]);
      MAC16(a4,b4)
    }
    __syncthreads();
  }
  int col = n0 + (tx<<2);
  float4 bb = *(const float4*)(bias + col);
#pragma unroll
  for (int i = 0; i < 4; i++){
    float4 v = make_float4(acc[i][0]+bb.x, acc[i][1]+bb.y, acc[i][2]+bb.z, acc[i][3]+bb.w);
    *(float4*)(C + (long)(m0+(ty<<2)+i)*N + col) = v;
  }
}

// 11) final: bn2+gelu, @ hc_w3 + hc_b3, softmax over 4 -> d_out
__global__ __launch_bounds__(256) void k_final(
    const float* __restrict__ h2, const float* __restrict__ mu,
    const float* __restrict__ rs, const float* __restrict__ gam,
    const float* __restrict__ bet, const float* __restrict__ w3,
    const float* __restrict__ b3, float* __restrict__ outp){
  int b = blockIdx.x, tid = threadIdx.x;
  float v = h2[(long)b*256 + tid];
  v = (v - mu[tid]) * rs[tid] * gam[tid] + bet[tid];
  v = gelu_exact(v);
  float4 w = ((const float4*)w3)[tid];
  float p0 = v*w.x, p1 = v*w.y, p2 = v*w.z, p3 = v*w.w;
#pragma unroll
  for (int o = 32; o > 0; o >>= 1){
    p0 += __shfl_down(p0, o);
    p1 += __shfl_down(p1, o);
    p2 += __shfl_down(p2, o);
    p3 += __shfl_down(p3, o);
  }
  __shared__ float red[4][4];
  int wv = tid >> 6;
  if ((tid & 63) == 0){ red[wv][0]=p0; red[wv][1]=p1; red[wv][2]=p2; red[wv][3]=p3; }
  __syncthreads();
  if (tid == 0){
    float l[4];
#pragma unroll
    for (int c = 0; c < 4; c++)
      l[c] = red[0][c]+red[1][c]+red[2][c]+red[3][c] + b3[c];
    float m = fmaxf(fmaxf(l[0], l[1]), fmaxf(l[2], l[3]));
    float e[4]; float sum = 0.f;
#pragma unroll
    for (int c = 0; c < 4; c++){ e[c] = expf(l[c]-m); sum += e[c]; }
    float inv = 1.f / sum;
#pragma unroll
    for (int c = 0; c < 4; c++) outp[(long)b*4 + c] = e[c]*inv;
  }
}

// ---------------------------------------------------------------------------
// Workspace layout (byte offsets), peak ~254 MB (round-1 proved >=324 MB ok):
//  GT    [0,          32,505,856)  fp32 62x131072         dead after region
//  XCAT  [32,505,856, 81,264,640)  bf16 63488x384         dead after cheby1
//  AGT   [81,264,640, 113,770,496) fp32                   dead after spread2
//  G2IN  [113,770,496,124,256,256) fp32 1024x2560         dead after x2cat
//  X2CAT [124,256,256,139,984,896) bf16 10240x768         dead after cheby2
//  W1T   [139,984,896,177,733,632) bf16 512x36864         live to h1 gemm
//  WC1T  [177,733,632,178,126,848) bf16 512x384
//  WC2T  [178,126,848,178,913,280) bf16 512x768
//  G1    [178,913,280,243,924,992) bf16 63488x512         dead after softcat
//  G2    [243,924,992,254,410,752) bf16 10240x512         dead after softcat
//  OUTB  alias [0, 75,497,472)     bf16 1024x36864   (GT+XCAT dead)
//  P     alias [81,264,640, 114,819,072) fp32 16x1024x512 (AGT+G2IN-head dead)
//  H1    alias [121,634,816, ...)  fp32 1024x512
//  H2    alias [123,731,968, ...)  fp32 1024x256
//  MU/RS alias [124,780,544, ...)
// ---------------------------------------------------------------------------
extern "C" void kernel_launch(void* const* d_in, const int* in_sizes, int n_in,
                              void* d_out, int out_size, void* d_ws, size_t ws_size,
                              hipStream_t stream){
  (void)n_in; (void)out_size; (void)ws_size;
  bool dictOrder = (in_sizes[9] == 2560);
  const float* x     = (const float*)d_in[0];
  const float* tfe_w = (const float*)d_in[1];
  const float* tfe_b = (const float*)d_in[2];
  const float* ch1w  = (const float*)d_in[3];
  const float* Amat  = (const float*)d_in[4];
  const float* ch2w  = (const float*)d_in[5];
  const float* A1mat = (const float*)d_in[6];
  const float* bgate = (const float*)d_in[7];
  const float* cgate = (const float*)d_in[8];
  const float* regb  = (const float*)d_in[dictOrder ? 9 : 19];
  int o = dictOrder ? 0 : 10;
  const float* hc_w1 = (const float*)d_in[10+o];
  const float* hc_b1 = (const float*)d_in[11+o];
  const float* bn1g  = (const float*)d_in[12+o];
  const float* bn1b  = (const float*)d_in[13+o];
  const float* hc_w2 = (const float*)d_in[14+o];
  const float* hc_b2 = (const float*)d_in[15+o];
  const float* bn2g  = (const float*)d_in[16+o];
  const float* bn2b  = (const float*)d_in[17+o];
  const float* hc_w3 = (const float*)d_in[18+o];
  const float* hc_b3 = (const float*)d_in[19+o];
  Ptr10 rws;
  for (int i = 0; i < 10; i++) rws.p[i] = (const float*)d_in[(dictOrder ? 20 : 9) + i];

  char* Wb = (char*)d_ws;
  float*          GT    = (float*)(Wb + 0);
  unsigned short* XCAT  = (unsigned short*)(Wb + 32505856);
  float*          AGT   = (float*)(Wb + 81264640);
  float*          G2IN  = (float*)(Wb + 113770496);
  unsigned short* X2CAT = (unsigned short*)(Wb + 124256256);
  unsigned short* W1T   = (unsigned short*)(Wb + 139984896);
  unsigned short* WC1T  = (unsigned short*)(Wb + 177733632);
  unsigned short* WC2T  = (unsigned short*)(Wb + 178126848);
  unsigned short* G1    = (unsigned short*)(Wb + 178913280);
  unsigned short* G2    = (unsigned short*)(Wb + 243924992);
  unsigned short* OUTB  = (unsigned short*)(Wb + 0);
  float*          P     = (float*)(Wb + 81264640);
  float*          H1    = (float*)(Wb + 121634816);
  float*          H2    = (float*)(Wb + 123731968);
  float*          MU1   = (float*)(Wb + 124780544);
  float*          RS1   = MU1 + 512;
  float*          MU2   = MU1 + 1024;
  float*          RS2   = MU1 + 1280;

  // weight prep (per call; no persistent state allowed)
  k_transpose_bf16<<<dim3(16,1152), 256, 0, stream>>>(hc_w1, W1T, 36864, 512);
  k_transpose_bf16<<<dim3(16,12),   256, 0, stream>>>(ch1w,  WC1T, 384, 512);
  k_transpose_bf16<<<dim3(16,24),   256, 0, stream>>>(ch2w,  WC2T, 768, 512);

  k_g<<<1024*62, 128, 0, stream>>>(x, tfe_w, tfe_b, GT, XCAT);
  k_spread_gemm<<<2048, 256, 0, stream>>>(Amat, GT, AGT, XCAT, 1);
  k_spread_gemm<<<2048, 256, 0, stream>>>(Amat, AGT, nullptr, XCAT, 2);
  k_gemm_region<<<dim3(16,4,10), 256, 0, stream>>>(GT, rws, regb, G2IN);
  k_x2cat<<<1024, 256, 0, stream>>>(G2IN, A1mat, X2CAT);
  // cheby2: (10240 x 768) @ (768 x 512) -> G2 bf16 (relu)
  k_mfma<true><<<dim3(80,4,1), 256, 0, stream>>>(X2CAT, 768, WC2T, 768, (void*)G2, 512, 768, 0);
  // cheby1: (63488 x 384) @ (384 x 512) -> G1 bf16 (relu)
  k_mfma<true><<<dim3(496,4,1), 256, 0, stream>>>(XCAT, 384, WC1T, 384, (void*)G1, 512, 384, 0);
  k_softcat<<<dim3(1024,4), 128, 0, stream>>>(G1, G2, bgate, cgate, OUTB);
  // h1: (1024 x 36864) @ (36864 x 512), split-K=16 -> P fp32
  k_mfma<false><<<dim3(8,4,16), 256, 0, stream>>>(OUTB, 36864, W1T, 36864, (void*)P, 512, 2304, 524288);
  k_reduce<<<2048, 256, 0, stream>>>(P, hc_b1, H1);
  k_stats<<<512, 256, 0, stream>>>(H1, 512, MU1, RS1);
  k_gemm_h2<<<dim3(16,4), 256, 0, stream>>>(H1, hc_w2, MU1, RS1, bn1g, bn1b, hc_b2, H2);
  k_stats<<<256, 256, 0, stream>>>(H2, 256, MU2, RS2);
  k_final<<<1024, 256, 0, stream>>>(H2, MU2, RS2, bn2g, bn2b, hc_w3, hc_b3, (float*)d_out);
}